// Round 8
// baseline (723.036 us; speedup 1.0000x reference)
//
#include <hip/hip_runtime.h>
#include <math.h>

#define B_ 4
#define N_ 256
#define D_ 128
#define H_ 256
#define K_ 8
#define NJP2 32    // j per phase (8 phases)
#define ALO2 4096  // shorts offset of lo half in a_all

typedef short v8s __attribute__((ext_vector_type(8)));    // 8 bf16 = 4 VGPRs
typedef float v16f __attribute__((ext_vector_type(16)));  // 32x32 MFMA acc

// hi = top-16-bit truncation (x - hi is EXACT); lo = RNE bf16 of remainder.
__device__ inline void split_bf16(float x, unsigned short& hi, unsigned short& lo) {
  unsigned u = __float_as_uint(x);
  unsigned uh = u & 0xFFFF0000u;
  hi = (unsigned short)(uh >> 16);
  float r = x - __uint_as_float(uh);
  unsigned ur = __float_as_uint(r);
  ur += 0x7FFFu + ((ur >> 16) & 1u);
  lo = (unsigned short)(ur >> 16);
}

// ---------------------------------------------------------------------------
// prep_all v19 (unchanged in v20):
//  blocks 0..255  : Ag/Aa (i-side + bias) AND Bg/Ba (j-side), 4 n/block.
//  blocks 256..319: W3 (P-part weights only, ks 0..7) -> interleaved MFMA-B
//                   frag order [ks(8)][tile(8)][{ghi,glo,ahi}][lane][8]
// ---------------------------------------------------------------------------
__global__ __launch_bounds__(256) void prep_all(
    const float* __restrict__ s,
    const float* __restrict__ Wg1, const float* __restrict__ bg1,
    const float* __restrict__ Wa1, const float* __restrict__ ba1,
    float* __restrict__ Ag, float* __restrict__ Aa,
    float* __restrict__ Bg, float* __restrict__ Ba,
    unsigned short* __restrict__ W3) {
  const int blk = blockIdx.x;
  if (blk < 256) {
    __shared__ float sh4[4][D_];
    const int b = blk >> 6, n0 = (blk & 63) * 4;
    {
      const int r = threadIdx.x >> 7, d = threadIdx.x & 127;  // r 0..1
      sh4[r][d] = s[(b * N_ + n0 + r) * D_ + d];
      sh4[r + 2][d] = s[(b * N_ + n0 + r + 2) * D_ + d];
    }
    __syncthreads();
    const int h = threadIdx.x;
    float ag[4], bgv[4], aa[4], bav[4];
#pragma unroll
    for (int n = 0; n < 4; n++) {
      ag[n] = bg1[h]; aa[n] = ba1[h]; bgv[n] = 0.f; bav[n] = 0.f;
    }
#pragma unroll 2
    for (int d = 0; d < D_; d++) {
      const float wg0 = Wg1[d * H_ + h];
      const float wg1 = Wg1[(D_ + d) * H_ + h];
      const float wa0 = Wa1[d * H_ + h];
      const float wa1 = Wa1[(D_ + d) * H_ + h];
#pragma unroll
      for (int n = 0; n < 4; n++) {
        const float sv = sh4[n][d];
        ag[n] = fmaf(sv, wg0, ag[n]);
        bgv[n] = fmaf(sv, wg1, bgv[n]);
        aa[n] = fmaf(sv, wa0, aa[n]);
        bav[n] = fmaf(sv, wa1, bav[n]);
      }
    }
#pragma unroll
    for (int n = 0; n < 4; n++) {
      const int o = (b * N_ + n0 + n) * H_ + h;
      Ag[o] = ag[n]; Bg[o] = bgv[n]; Aa[o] = aa[n]; Ba[o] = bav[n];
    }
  } else {
    const int id = blk - 256;           // 0..63 = ks*8 + tile
    if (threadIdx.x < 64) {
      const int ks = id >> 3, tile = id & 7, lane = threadIdx.x;
      const int h = tile * 32 + (lane & 31);
      const int kbase = ks * 16 + (lane >> 5) * 8;
      const int idx0 = id * 1536 + lane * 8;   // slab = 3*512 shorts
#pragma unroll
      for (int e = 0; e < 8; e++) {
        const int f = 2 * D_ + kbase + e;      // P-part rows only
        unsigned short x, y;
        split_bf16(Wg1[f * H_ + h], x, y);
        W3[idx0 + e] = x;          // gate hi  (+0 B)
        W3[idx0 + 512 + e] = y;    // gate lo  (+1024 B)
        unsigned short xa, ya;
        split_bf16(Wa1[f * H_ + h], xa, ya);
        W3[idx0 + 1024 + e] = xa;  // att hi   (+2048 B)
      }
    }
  }
}

__device__ inline void arg_better(float v2, int i2, float& v, int& idx) {
  if (v2 > v || (v2 == v && i2 < idx)) { v = v2; idx = i2; }
}

// ---------------------------------------------------------------------------
// score_kernel v20 = v19 + XCD-aware blockIdx swizzle.
//  v19 post-mortem: FETCH 1.03GB, HBM 2TB/s, MfmaUtil 4% — the new Bg/Ba
//  epilogue stream thrashed the per-XCD L2 (round-robin dispatch put all 4
//  batches' working sets (~8MB) on every 4MB L2). Swizzle gives each XCD a
//  CONTIGUOUS run of 128 logical blocks (half of one batch): working set
//  ~1.1MB -> Bg/Ba reads become L2 hits. v19 structure otherwise unchanged
//  (halved MFMA work via precomputed j-side first layer, 3 blocks/CU,
//  no spill).
// ---------------------------------------------------------------------------
__global__ __launch_bounds__(256, 3) void score_kernel(
    const float* __restrict__ s,
    const float* __restrict__ Ag, const float* __restrict__ Aa,
    const float* __restrict__ Bg, const float* __restrict__ Ba,
    const unsigned short* __restrict__ W3,
    const float* __restrict__ Wg2, const float* __restrict__ bg2p,
    const float* __restrict__ Wa2, const float* __restrict__ ba2p,
    float* __restrict__ out) {
  // XCD swizzle: HW places workgroup w on XCD w%8; relabel so XCD c gets
  // logical blocks [c*128, c*128+128) in dispatch order. Bijective (1024%8==0).
  const int wg = blockIdx.x;
  const int lg = (wg & 7) * 128 + (wg >> 3);
  const int b = lg >> 8;
  const int i = lg & 255;
  const int t = threadIdx.x;
  const int wv = t >> 6, lane = t & 63;
  const int m32 = lane & 31, half32 = lane >> 5;

  __shared__ __align__(16) unsigned short a_all[2 * ALO2 + 64]; // P hi|lo 16KB
  __shared__ float si_sh[D_];
  __shared__ float sc_part[8 * NJP2];  // [0..3]=gate per wave, [4..7]=att
  __shared__ float scg_sh[N_];
  __shared__ float attl_sh[N_];
  __shared__ float red_v[4];
  __shared__ int red_i[4];
  __shared__ int sel_list[K_];

  if (t < D_) si_sh[t] = s[(b * N_ + i) * D_ + t];

#define MF(A_, B_v, C_) C_ = __builtin_amdgcn_mfma_f32_32x32x16_bf16(A_, B_v, C_, 0, 0, 0)

#pragma unroll 1
  for (int ph = 0; ph < 8; ph++) {
    __syncthreads();
    // ---- stage P tile (frag order): 32 j x 128 k, hi/lo ----
    {
      const int jl = t >> 3, kq = t & 7;      // 32 jl x 8 kq, 16 k each
      const float* srow = s + (b * N_ + ph * NJP2 + jl) * D_ + kq * 16;
      const float* sic = si_sh + kq * 16;
#pragma unroll
      for (int u = 0; u < 2; u++) {   // 8 k per u
        const float4 sv0 = *(const float4*)(srow + u * 8);
        const float4 sv1 = *(const float4*)(srow + u * 8 + 4);
        v8s vph, vpl;
        unsigned short x, y;
        split_bf16(sic[u * 8 + 0] * sv0.x, x, y); vph[0] = (short)x; vpl[0] = (short)y;
        split_bf16(sic[u * 8 + 1] * sv0.y, x, y); vph[1] = (short)x; vpl[1] = (short)y;
        split_bf16(sic[u * 8 + 2] * sv0.z, x, y); vph[2] = (short)x; vpl[2] = (short)y;
        split_bf16(sic[u * 8 + 3] * sv0.w, x, y); vph[3] = (short)x; vpl[3] = (short)y;
        split_bf16(sic[u * 8 + 4] * sv1.x, x, y); vph[4] = (short)x; vpl[4] = (short)y;
        split_bf16(sic[u * 8 + 5] * sv1.y, x, y); vph[5] = (short)x; vpl[5] = (short)y;
        split_bf16(sic[u * 8 + 6] * sv1.z, x, y); vph[6] = (short)x; vpl[6] = (short)y;
        split_bf16(sic[u * 8 + 7] * sv1.w, x, y); vph[7] = (short)x; vpl[7] = (short)y;
        const int idx = (kq * 64 + u * 32 + jl) * 8;
        *(v8s*)(a_all + idx) = vph;
        *(v8s*)(a_all + ALO2 + idx) = vpl;
      }
    }
    __syncthreads();

    // ===== k-loop: gate (split-3) + att (hi); 2 h-tiles per wave =====
    v16f g0, g1, a0, a1;                     // [ht] — 64 AGPR
    g0 = g1 = (v16f)(0.f);
    a0 = a1 = (v16f)(0.f);

    {
      const unsigned short* wp0 = W3 + (2 * wv) * 1536 + lane * 8;
      const unsigned short* wp1 = wp0 + 1536;
      v8s bh[2][2], bl[2][2], bax[2][2];     // [slot][ht] ring, distance 2
      bh[0][0] = *(const v8s*)(wp0); bl[0][0] = *(const v8s*)(wp0 + 512); bax[0][0] = *(const v8s*)(wp0 + 1024);
      bh[0][1] = *(const v8s*)(wp1); bl[0][1] = *(const v8s*)(wp1 + 512); bax[0][1] = *(const v8s*)(wp1 + 1024);
      wp0 += 12288; wp1 += 12288;
      bh[1][0] = *(const v8s*)(wp0); bl[1][0] = *(const v8s*)(wp0 + 512); bax[1][0] = *(const v8s*)(wp0 + 1024);
      bh[1][1] = *(const v8s*)(wp1); bl[1][1] = *(const v8s*)(wp1 + 512); bax[1][1] = *(const v8s*)(wp1 + 1024);
      wp0 += 12288; wp1 += 12288;

      const unsigned short* ahp = a_all + lane * 8;
#pragma unroll
      for (int ks = 0; ks < 8; ks++) {
        const int cur = ks & 1;
        const v8s ah0 = *(const v8s*)(ahp);
        const v8s al0 = *(const v8s*)(ahp + ALO2);
        ahp += 512;
        MF(ah0, bh[cur][0], g0); MF(ah0, bax[cur][0], a0);
        MF(ah0, bh[cur][1], g1); MF(ah0, bax[cur][1], a1);
        MF(ah0, bl[cur][0], g0); MF(al0, bh[cur][0], g0);
        MF(ah0, bl[cur][1], g1); MF(al0, bh[cur][1], g1);
        // prefetch ks+2 into the slot just consumed (rows 8,9 = pad)
        bh[cur][0] = *(const v8s*)(wp0); bl[cur][0] = *(const v8s*)(wp0 + 512); bax[cur][0] = *(const v8s*)(wp0 + 1024);
        bh[cur][1] = *(const v8s*)(wp1); bl[cur][1] = *(const v8s*)(wp1 + 512); bax[cur][1] = *(const v8s*)(wp1 + 1024);
        wp0 += 12288; wp1 += 12288;
      }
    }

    // ---- epilogue: relu(acc + Ag[i,h] + Bg[j,h]) @ W2, both h-tiles fused
    //      before a single 32-lane butterfly (sum over h) ----
    {
      const int hg0 = wv * 64 + m32, hg1 = hg0 + 32;
      const int irow = (b * N_ + i) * H_;
      const float agv0 = Ag[irow + hg0], agv1 = Ag[irow + hg1];
      const float w2g0 = Wg2[hg0], w2g1 = Wg2[hg1];
      const float aav0 = Aa[irow + hg0], aav1 = Aa[irow + hg1];
      const float w2a0 = Wa2[hg0], w2a1 = Wa2[hg1];
      const float* bgrow = Bg + (b * N_ + ph * NJP2) * H_;
      const float* barow = Ba + (b * N_ + ph * NJP2) * H_;

#define EPI8C(C0_, C1_, R0_, BIAS0_, BIAS1_, W20_, W21_, BROW_, ROWOFF_) do { \
      float sv_[8];                                                           \
      _Pragma("unroll")                                                       \
      for (int rr_ = 0; rr_ < 8; rr_++) {                                     \
        const int r_ = (R0_) + rr_;                                           \
        const int jl_ = (r_ & 3) + 8 * (r_ >> 2) + 4 * half32;                \
        const float b0_ = BROW_[jl_ * H_ + hg0];                              \
        const float b1_ = BROW_[jl_ * H_ + hg1];                              \
        sv_[rr_] = fmaxf(C0_[r_] + (BIAS0_) + b0_, 0.f) * (W20_)              \
                 + fmaxf(C1_[r_] + (BIAS1_) + b1_, 0.f) * (W21_);             \
      }                                                                       \
      _Pragma("unroll")                                                       \
      for (int rr_ = 0; rr_ < 8; rr_++) {                                     \
        float v_ = sv_[rr_];                                                  \
        _Pragma("unroll")                                                     \
        for (int o_ = 1; o_ <= 16; o_ <<= 1) v_ += __shfl_xor(v_, o_, 64);    \
        sv_[rr_] = v_;                                                        \
      }                                                                       \
      if (m32 == 0) {                                                         \
        _Pragma("unroll")                                                     \
        for (int rr_ = 0; rr_ < 8; rr_++) {                                   \
          const int r_ = (R0_) + rr_;                                         \
          const int jl_ = (r_ & 3) + 8 * (r_ >> 2) + 4 * half32;              \
          sc_part[(ROWOFF_) + jl_] = sv_[rr_];                                \
        }                                                                     \
      }                                                                       \
    } while (0)

      EPI8C(g0, g1, 0, agv0, agv1, w2g0, w2g1, bgrow, wv * NJP2);
      EPI8C(g0, g1, 8, agv0, agv1, w2g0, w2g1, bgrow, wv * NJP2);
      EPI8C(a0, a1, 0, aav0, aav1, w2a0, w2a1, barow, 4 * NJP2 + wv * NJP2);
      EPI8C(a0, a1, 8, aav0, aav1, w2a0, w2a1, barow, 4 * NJP2 + wv * NJP2);
#undef EPI8C
    }
    __syncthreads();
    if (t < NJP2) {
      float sG = bg2p[0], sA = ba2p[0];
#pragma unroll
      for (int w = 0; w < 4; w++) {
        sG += sc_part[w * NJP2 + t];
        sA += sc_part[(4 + w) * NJP2 + t];
      }
      scg_sh[ph * NJP2 + t] = sG;
      attl_sh[ph * NJP2 + t] = sA;
    }
  }
  __syncthreads();

  // ---- top-8 over j: value desc, index asc ----
  for (int k = 0; k < K_; k++) {
    float v = scg_sh[t];
    int idx = t;
#pragma unroll
    for (int off = 32; off > 0; off >>= 1) {
      const float vo = __shfl_down(v, off, 64);
      const int io = __shfl_down(idx, off, 64);
      arg_better(vo, io, v, idx);
    }
    if ((t & 63) == 0) { red_v[t >> 6] = v; red_i[t >> 6] = idx; }
    __syncthreads();
    if (t == 0) {
      float bv = red_v[0];
      int bi = red_i[0];
      for (int w = 1; w < 4; w++) arg_better(red_v[w], red_i[w], bv, bi);
      sel_list[k] = bi;
      scg_sh[bi] = -INFINITY;
    }
    __syncthreads();
  }

  bool selj = false;
#pragma unroll
  for (int k = 0; k < K_; k++) selj = selj || (sel_list[k] == t);

  if (t == 0) {
    float m = -INFINITY;
    for (int k = 0; k < K_; k++) m = fmaxf(m, attl_sh[sel_list[k]]);
    float ssum = 0.f;
    for (int k = 0; k < K_; k++) ssum += expf(attl_sh[sel_list[k]] - m);
    red_v[0] = m;
    red_v[1] = ssum;
  }
  __syncthreads();
  const float att = selj ? expf(attl_sh[t] - red_v[0]) / red_v[1] : 0.f;

  float* __restrict__ ctx_out = out;
  float* __restrict__ gate_out = out + B_ * N_ * D_;
  float* __restrict__ att_out = out + B_ * N_ * D_ + B_ * N_ * N_;

  const int row = (b * N_ + i) * N_;
  gate_out[row + t] = selj ? 1.f : 0.f;
  att_out[row + t] = att;

  __syncthreads();
  attl_sh[t] = att;
  __syncthreads();

  if (t < D_) {
    float acc2 = 0.f;
#pragma unroll
    for (int k = 0; k < K_; k++) {
      const int jj = sel_list[k];
      acc2 = fmaf(attl_sh[jj], s[(b * N_ + jj) * D_ + t], acc2);
    }
    ctx_out[(b * N_ + i) * D_ + t] = acc2;
  }
#undef MF
}

extern "C" void kernel_launch(void* const* d_in, const int* in_sizes, int n_in,
                              void* d_out, int out_size, void* d_ws, size_t ws_size,
                              hipStream_t stream) {
  const float* s   = (const float*)d_in[0];
  const float* Wg1 = (const float*)d_in[1];
  const float* bg1 = (const float*)d_in[2];
  const float* Wg2 = (const float*)d_in[3];
  const float* bg2 = (const float*)d_in[4];
  const float* Wa1 = (const float*)d_in[5];
  const float* ba1 = (const float*)d_in[6];
  const float* Wa2 = (const float*)d_in[7];
  const float* ba2 = (const float*)d_in[8];
  float* out = (float*)d_out;

  float* ws = (float*)d_ws;
  float* Ag = ws;                          // B*N*H floats (i-side gate + bias)
  float* Aa = Ag + B_ * N_ * H_;           // B*N*H floats (i-side att + bias)
  float* Bg = Aa + B_ * N_ * H_;           // B*N*H floats (j-side gate)
  float* Ba = Bg + B_ * N_ * H_;           // B*N*H floats (j-side att)
  // W3: 8 ks rows * 12288 shorts + 2 pad rows (distance-2 prefetch overrun)
  unsigned short* W3 = (unsigned short*)(Ba + B_ * N_ * H_);  // 10*12288 shorts

  prep_all<<<dim3(320), dim3(256), 0, stream>>>(
      s, Wg1, bg1, Wa1, ba1, Ag, Aa, Bg, Ba, W3);
  score_kernel<<<dim3(B_ * N_), dim3(256), 0, stream>>>(
      s, Ag, Aa, Bg, Ba, W3, Wg2, bg2, Wa2, ba2, out);
}

// Round 9
// 511.340 us; speedup vs baseline: 1.4140x; 1.4140x over previous
//
#include <hip/hip_runtime.h>
#include <math.h>

#define B_ 4
#define N_ 256
#define D_ 128
#define H_ 256
#define K_ 8
#define NJP2 32    // j per phase (8 phases)
#define ALO2 4096  // shorts offset of lo half in a_all

typedef short v8s __attribute__((ext_vector_type(8)));    // 8 bf16 = 4 VGPRs
typedef float v16f __attribute__((ext_vector_type(16)));  // 32x32 MFMA acc

// hi = top-16-bit truncation (x - hi is EXACT); lo = RNE bf16 of remainder.
__device__ inline void split_bf16(float x, unsigned short& hi, unsigned short& lo) {
  unsigned u = __float_as_uint(x);
  unsigned uh = u & 0xFFFF0000u;
  hi = (unsigned short)(uh >> 16);
  float r = x - __uint_as_float(uh);
  unsigned ur = __float_as_uint(r);
  ur += 0x7FFFu + ((ur >> 16) & 1u);
  lo = (unsigned short)(ur >> 16);
}

// ---------------------------------------------------------------------------
// prep_all (unchanged from v19/v20):
//  blocks 0..255  : Ag/Aa (i-side + bias) AND Bg/Ba (j-side), 4 n/block.
//  blocks 256..319: W3 (P-part weights only, ks 0..7) -> interleaved MFMA-B
//                   frag order [ks(8)][tile(8)][{ghi,glo,ahi}][lane][8]
// ---------------------------------------------------------------------------
__global__ __launch_bounds__(256) void prep_all(
    const float* __restrict__ s,
    const float* __restrict__ Wg1, const float* __restrict__ bg1,
    const float* __restrict__ Wa1, const float* __restrict__ ba1,
    float* __restrict__ Ag, float* __restrict__ Aa,
    float* __restrict__ Bg, float* __restrict__ Ba,
    unsigned short* __restrict__ W3) {
  const int blk = blockIdx.x;
  if (blk < 256) {
    __shared__ float sh4[4][D_];
    const int b = blk >> 6, n0 = (blk & 63) * 4;
    {
      const int r = threadIdx.x >> 7, d = threadIdx.x & 127;  // r 0..1
      sh4[r][d] = s[(b * N_ + n0 + r) * D_ + d];
      sh4[r + 2][d] = s[(b * N_ + n0 + r + 2) * D_ + d];
    }
    __syncthreads();
    const int h = threadIdx.x;
    float ag[4], bgv[4], aa[4], bav[4];
#pragma unroll
    for (int n = 0; n < 4; n++) {
      ag[n] = bg1[h]; aa[n] = ba1[h]; bgv[n] = 0.f; bav[n] = 0.f;
    }
#pragma unroll 2
    for (int d = 0; d < D_; d++) {
      const float wg0 = Wg1[d * H_ + h];
      const float wg1 = Wg1[(D_ + d) * H_ + h];
      const float wa0 = Wa1[d * H_ + h];
      const float wa1 = Wa1[(D_ + d) * H_ + h];
#pragma unroll
      for (int n = 0; n < 4; n++) {
        const float sv = sh4[n][d];
        ag[n] = fmaf(sv, wg0, ag[n]);
        bgv[n] = fmaf(sv, wg1, bgv[n]);
        aa[n] = fmaf(sv, wa0, aa[n]);
        bav[n] = fmaf(sv, wa1, bav[n]);
      }
    }
#pragma unroll
    for (int n = 0; n < 4; n++) {
      const int o = (b * N_ + n0 + n) * H_ + h;
      Ag[o] = ag[n]; Bg[o] = bgv[n]; Aa[o] = aa[n]; Ba[o] = bav[n];
    }
  } else {
    const int id = blk - 256;           // 0..63 = ks*8 + tile
    if (threadIdx.x < 64) {
      const int ks = id >> 3, tile = id & 7, lane = threadIdx.x;
      const int h = tile * 32 + (lane & 31);
      const int kbase = ks * 16 + (lane >> 5) * 8;
      const int idx0 = id * 1536 + lane * 8;   // slab = 3*512 shorts
#pragma unroll
      for (int e = 0; e < 8; e++) {
        const int f = 2 * D_ + kbase + e;      // P-part rows only
        unsigned short x, y;
        split_bf16(Wg1[f * H_ + h], x, y);
        W3[idx0 + e] = x;          // gate hi  (+0 B)
        W3[idx0 + 512 + e] = y;    // gate lo  (+1024 B)
        unsigned short xa, ya;
        split_bf16(Wa1[f * H_ + h], xa, ya);
        W3[idx0 + 1024 + e] = xa;  // att hi   (+2048 B)
      }
    }
  }
}

__device__ inline void arg_better(float v2, int i2, float& v, int& idx) {
  if (v2 > v || (v2 == v && i2 < idx)) { v = v2; idx = i2; }
}

// ---------------------------------------------------------------------------
// score_kernel v21 = v20 at the NO-SPILL register tier.
//  v20 post-mortem: WRITE 263MB (outputs are 2.6MB) = scratch spill at the
//  (256,3) 168-reg cap; scratch stream thrashed L2 -> Bg/Ba missed -> FETCH
//  1GB; swizzle null (private traffic). Register ledger across v16-v20:
//  cap 128 spills, cap 168 spills, cap 256 clean (v18: 144 used, WRITE
//  2.5MB). So: __launch_bounds__(256,2) -> 256 regs/wave, 2 blocks/CU =
//  8 waves/CU (v14's proven TLP). Ring rewritten with NAMED slot vars
//  (literal indices; immune to rule-#20 dynamic-index scratch).
// ---------------------------------------------------------------------------
__global__ __launch_bounds__(256, 2) void score_kernel(
    const float* __restrict__ s,
    const float* __restrict__ Ag, const float* __restrict__ Aa,
    const float* __restrict__ Bg, const float* __restrict__ Ba,
    const unsigned short* __restrict__ W3,
    const float* __restrict__ Wg2, const float* __restrict__ bg2p,
    const float* __restrict__ Wa2, const float* __restrict__ ba2p,
    float* __restrict__ out) {
  // XCD swizzle: HW places workgroup w on XCD w%8; relabel so XCD c gets
  // logical blocks [c*128, c*128+128) in dispatch order. Bijective (1024%8==0).
  const int wg = blockIdx.x;
  const int lg = (wg & 7) * 128 + (wg >> 3);
  const int b = lg >> 8;
  const int i = lg & 255;
  const int t = threadIdx.x;
  const int wv = t >> 6, lane = t & 63;
  const int m32 = lane & 31, half32 = lane >> 5;

  __shared__ __align__(16) unsigned short a_all[2 * ALO2 + 64]; // P hi|lo 16KB
  __shared__ float si_sh[D_];
  __shared__ float sc_part[8 * NJP2];  // [0..3]=gate per wave, [4..7]=att
  __shared__ float scg_sh[N_];
  __shared__ float attl_sh[N_];
  __shared__ float red_v[4];
  __shared__ int red_i[4];
  __shared__ int sel_list[K_];

  if (t < D_) si_sh[t] = s[(b * N_ + i) * D_ + t];

#define MF(A_, B_v, C_) C_ = __builtin_amdgcn_mfma_f32_32x32x16_bf16(A_, B_v, C_, 0, 0, 0)

#pragma unroll 1
  for (int ph = 0; ph < 8; ph++) {
    __syncthreads();
    // ---- stage P tile (frag order): 32 j x 128 k, hi/lo ----
    {
      const int jl = t >> 3, kq = t & 7;      // 32 jl x 8 kq, 16 k each
      const float* srow = s + (b * N_ + ph * NJP2 + jl) * D_ + kq * 16;
      const float* sic = si_sh + kq * 16;
#pragma unroll
      for (int u = 0; u < 2; u++) {   // 8 k per u
        const float4 sv0 = *(const float4*)(srow + u * 8);
        const float4 sv1 = *(const float4*)(srow + u * 8 + 4);
        v8s vph, vpl;
        unsigned short x, y;
        split_bf16(sic[u * 8 + 0] * sv0.x, x, y); vph[0] = (short)x; vpl[0] = (short)y;
        split_bf16(sic[u * 8 + 1] * sv0.y, x, y); vph[1] = (short)x; vpl[1] = (short)y;
        split_bf16(sic[u * 8 + 2] * sv0.z, x, y); vph[2] = (short)x; vpl[2] = (short)y;
        split_bf16(sic[u * 8 + 3] * sv0.w, x, y); vph[3] = (short)x; vpl[3] = (short)y;
        split_bf16(sic[u * 8 + 4] * sv1.x, x, y); vph[4] = (short)x; vpl[4] = (short)y;
        split_bf16(sic[u * 8 + 5] * sv1.y, x, y); vph[5] = (short)x; vpl[5] = (short)y;
        split_bf16(sic[u * 8 + 6] * sv1.z, x, y); vph[6] = (short)x; vpl[6] = (short)y;
        split_bf16(sic[u * 8 + 7] * sv1.w, x, y); vph[7] = (short)x; vpl[7] = (short)y;
        const int idx = (kq * 64 + u * 32 + jl) * 8;
        *(v8s*)(a_all + idx) = vph;
        *(v8s*)(a_all + ALO2 + idx) = vpl;
      }
    }
    __syncthreads();

    // ===== k-loop: gate (split-3) + att (hi); 2 h-tiles per wave =====
    v16f g0, g1, a0, a1;                     // [ht] — 64 AGPR
    g0 = g1 = (v16f)(0.f);
    a0 = a1 = (v16f)(0.f);

    {
      const unsigned short* wp0 = W3 + (2 * wv) * 1536 + lane * 8;
      const unsigned short* wp1 = wp0 + 1536;
      // distance-2 ring, NAMED slots (all indices literal)
      v8s sA_h0, sA_l0, sA_a0, sA_h1, sA_l1, sA_a1;   // slot A: [ht0],[ht1]
      v8s sB_h0, sB_l0, sB_a0, sB_h1, sB_l1, sB_a1;   // slot B
      sA_h0 = *(const v8s*)(wp0); sA_l0 = *(const v8s*)(wp0 + 512); sA_a0 = *(const v8s*)(wp0 + 1024);
      sA_h1 = *(const v8s*)(wp1); sA_l1 = *(const v8s*)(wp1 + 512); sA_a1 = *(const v8s*)(wp1 + 1024);
      wp0 += 12288; wp1 += 12288;
      sB_h0 = *(const v8s*)(wp0); sB_l0 = *(const v8s*)(wp0 + 512); sB_a0 = *(const v8s*)(wp0 + 1024);
      sB_h1 = *(const v8s*)(wp1); sB_l1 = *(const v8s*)(wp1 + 512); sB_a1 = *(const v8s*)(wp1 + 1024);
      wp0 += 12288; wp1 += 12288;

      const unsigned short* ahp = a_all + lane * 8;
#pragma unroll
      for (int kk = 0; kk < 4; kk++) {
        // ---- ks = 2*kk : consume slot A, prefetch ks+2 into slot A ----
        {
          const v8s ah0 = *(const v8s*)(ahp);
          const v8s al0 = *(const v8s*)(ahp + ALO2);
          ahp += 512;
          MF(ah0, sA_h0, g0); MF(ah0, sA_a0, a0);
          MF(ah0, sA_h1, g1); MF(ah0, sA_a1, a1);
          MF(ah0, sA_l0, g0); MF(al0, sA_h0, g0);
          MF(ah0, sA_l1, g1); MF(al0, sA_h1, g1);
          sA_h0 = *(const v8s*)(wp0); sA_l0 = *(const v8s*)(wp0 + 512); sA_a0 = *(const v8s*)(wp0 + 1024);
          sA_h1 = *(const v8s*)(wp1); sA_l1 = *(const v8s*)(wp1 + 512); sA_a1 = *(const v8s*)(wp1 + 1024);
          wp0 += 12288; wp1 += 12288;   // ks=6 prefetches row 8 (pad)
        }
        // ---- ks = 2*kk+1 : consume slot B, prefetch ks+2 into slot B ----
        {
          const v8s ah0 = *(const v8s*)(ahp);
          const v8s al0 = *(const v8s*)(ahp + ALO2);
          ahp += 512;
          MF(ah0, sB_h0, g0); MF(ah0, sB_a0, a0);
          MF(ah0, sB_h1, g1); MF(ah0, sB_a1, a1);
          MF(ah0, sB_l0, g0); MF(al0, sB_h0, g0);
          MF(ah0, sB_l1, g1); MF(al0, sB_h1, g1);
          sB_h0 = *(const v8s*)(wp0); sB_l0 = *(const v8s*)(wp0 + 512); sB_a0 = *(const v8s*)(wp0 + 1024);
          sB_h1 = *(const v8s*)(wp1); sB_l1 = *(const v8s*)(wp1 + 512); sB_a1 = *(const v8s*)(wp1 + 1024);
          wp0 += 12288; wp1 += 12288;   // ks=7 prefetches row 9 (pad)
        }
      }
    }

    // ---- epilogue: relu(acc + Ag[i,h] + Bg[j,h]) @ W2, both h-tiles fused
    //      before a single 32-lane butterfly (sum over h) ----
    {
      const int hg0 = wv * 64 + m32, hg1 = hg0 + 32;
      const int irow = (b * N_ + i) * H_;
      const float agv0 = Ag[irow + hg0], agv1 = Ag[irow + hg1];
      const float w2g0 = Wg2[hg0], w2g1 = Wg2[hg1];
      const float aav0 = Aa[irow + hg0], aav1 = Aa[irow + hg1];
      const float w2a0 = Wa2[hg0], w2a1 = Wa2[hg1];
      const float* bgrow = Bg + (b * N_ + ph * NJP2) * H_;
      const float* barow = Ba + (b * N_ + ph * NJP2) * H_;

#define EPI8C(C0_, C1_, R0_, BIAS0_, BIAS1_, W20_, W21_, BROW_, ROWOFF_) do { \
      float sv_[8];                                                           \
      _Pragma("unroll")                                                       \
      for (int rr_ = 0; rr_ < 8; rr_++) {                                     \
        const int r_ = (R0_) + rr_;                                           \
        const int jl_ = (r_ & 3) + 8 * (r_ >> 2) + 4 * half32;                \
        const float b0_ = BROW_[jl_ * H_ + hg0];                              \
        const float b1_ = BROW_[jl_ * H_ + hg1];                              \
        sv_[rr_] = fmaxf(C0_[r_] + (BIAS0_) + b0_, 0.f) * (W20_)              \
                 + fmaxf(C1_[r_] + (BIAS1_) + b1_, 0.f) * (W21_);             \
      }                                                                       \
      _Pragma("unroll")                                                       \
      for (int rr_ = 0; rr_ < 8; rr_++) {                                     \
        float v_ = sv_[rr_];                                                  \
        _Pragma("unroll")                                                     \
        for (int o_ = 1; o_ <= 16; o_ <<= 1) v_ += __shfl_xor(v_, o_, 64);    \
        sv_[rr_] = v_;                                                        \
      }                                                                       \
      if (m32 == 0) {                                                         \
        _Pragma("unroll")                                                     \
        for (int rr_ = 0; rr_ < 8; rr_++) {                                   \
          const int r_ = (R0_) + rr_;                                         \
          const int jl_ = (r_ & 3) + 8 * (r_ >> 2) + 4 * half32;              \
          sc_part[(ROWOFF_) + jl_] = sv_[rr_];                                \
        }                                                                     \
      }                                                                       \
    } while (0)

      EPI8C(g0, g1, 0, agv0, agv1, w2g0, w2g1, bgrow, wv * NJP2);
      EPI8C(g0, g1, 8, agv0, agv1, w2g0, w2g1, bgrow, wv * NJP2);
      EPI8C(a0, a1, 0, aav0, aav1, w2a0, w2a1, barow, 4 * NJP2 + wv * NJP2);
      EPI8C(a0, a1, 8, aav0, aav1, w2a0, w2a1, barow, 4 * NJP2 + wv * NJP2);
#undef EPI8C
    }
    __syncthreads();
    if (t < NJP2) {
      float sG = bg2p[0], sA = ba2p[0];
#pragma unroll
      for (int w = 0; w < 4; w++) {
        sG += sc_part[w * NJP2 + t];
        sA += sc_part[(4 + w) * NJP2 + t];
      }
      scg_sh[ph * NJP2 + t] = sG;
      attl_sh[ph * NJP2 + t] = sA;
    }
  }
  __syncthreads();

  // ---- top-8 over j: value desc, index asc ----
  for (int k = 0; k < K_; k++) {
    float v = scg_sh[t];
    int idx = t;
#pragma unroll
    for (int off = 32; off > 0; off >>= 1) {
      const float vo = __shfl_down(v, off, 64);
      const int io = __shfl_down(idx, off, 64);
      arg_better(vo, io, v, idx);
    }
    if ((t & 63) == 0) { red_v[t >> 6] = v; red_i[t >> 6] = idx; }
    __syncthreads();
    if (t == 0) {
      float bv = red_v[0];
      int bi = red_i[0];
      for (int w = 1; w < 4; w++) arg_better(red_v[w], red_i[w], bv, bi);
      sel_list[k] = bi;
      scg_sh[bi] = -INFINITY;
    }
    __syncthreads();
  }

  bool selj = false;
#pragma unroll
  for (int k = 0; k < K_; k++) selj = selj || (sel_list[k] == t);

  if (t == 0) {
    float m = -INFINITY;
    for (int k = 0; k < K_; k++) m = fmaxf(m, attl_sh[sel_list[k]]);
    float ssum = 0.f;
    for (int k = 0; k < K_; k++) ssum += expf(attl_sh[sel_list[k]] - m);
    red_v[0] = m;
    red_v[1] = ssum;
  }
  __syncthreads();
  const float att = selj ? expf(attl_sh[t] - red_v[0]) / red_v[1] : 0.f;

  float* __restrict__ ctx_out = out;
  float* __restrict__ gate_out = out + B_ * N_ * D_;
  float* __restrict__ att_out = out + B_ * N_ * D_ + B_ * N_ * N_;

  const int row = (b * N_ + i) * N_;
  gate_out[row + t] = selj ? 1.f : 0.f;
  att_out[row + t] = att;

  __syncthreads();
  attl_sh[t] = att;
  __syncthreads();

  if (t < D_) {
    float acc2 = 0.f;
#pragma unroll
    for (int k = 0; k < K_; k++) {
      const int jj = sel_list[k];
      acc2 = fmaf(attl_sh[jj], s[(b * N_ + jj) * D_ + t], acc2);
    }
    ctx_out[(b * N_ + i) * D_ + t] = acc2;
  }
#undef MF
}

extern "C" void kernel_launch(void* const* d_in, const int* in_sizes, int n_in,
                              void* d_out, int out_size, void* d_ws, size_t ws_size,
                              hipStream_t stream) {
  const float* s   = (const float*)d_in[0];
  const float* Wg1 = (const float*)d_in[1];
  const float* bg1 = (const float*)d_in[2];
  const float* Wg2 = (const float*)d_in[3];
  const float* bg2 = (const float*)d_in[4];
  const float* Wa1 = (const float*)d_in[5];
  const float* ba1 = (const float*)d_in[6];
  const float* Wa2 = (const float*)d_in[7];
  const float* ba2 = (const float*)d_in[8];
  float* out = (float*)d_out;

  float* ws = (float*)d_ws;
  float* Ag = ws;                          // B*N*H floats (i-side gate + bias)
  float* Aa = Ag + B_ * N_ * H_;           // B*N*H floats (i-side att + bias)
  float* Bg = Aa + B_ * N_ * H_;           // B*N*H floats (j-side gate)
  float* Ba = Bg + B_ * N_ * H_;           // B*N*H floats (j-side att)
  // W3: 8 ks rows * 12288 shorts + 2 pad rows (distance-2 prefetch overrun)
  unsigned short* W3 = (unsigned short*)(Ba + B_ * N_ * H_);  // 10*12288 shorts

  prep_all<<<dim3(320), dim3(256), 0, stream>>>(
      s, Wg1, bg1, Wa1, ba1, Ag, Aa, Bg, Ba, W3);
  score_kernel<<<dim3(B_ * N_), dim3(256), 0, stream>>>(
      s, Ag, Aa, Bg, Ba, W3, Wg2, bg2, Wa2, ba2, out);
}